// Round 7
// baseline (143.303 us; speedup 1.0000x reference)
//
#include <hip/hip_runtime.h>
#include <hip/hip_bf16.h>

#define B_ 16
#define T_ 2048
#define C_ 384
#define H_ 64

typedef __attribute__((ext_vector_type(8))) short short8;
typedef __attribute__((ext_vector_type(4))) short short4_t;
typedef __attribute__((ext_vector_type(4))) float floatx4;

static __device__ __forceinline__ short f2bf(float f) {
    unsigned u = __builtin_bit_cast(unsigned, f);
    u += 0x7FFF + ((u >> 16) & 1);   // round-to-nearest-even
    return (short)(u >> 16);
}

// ---------------------------------------------------------------------------
// Kernel 0: weights fp32[C,H] -> bf16 in MFMA B-fragment order.
// wt2[nt16][kc32][lane][j]: frag for n-tile nt16 (= mat*4 + w), k-chunk kc32.
// lane = quad*16+l16 holds W[c = kc32*32+quad*8+j][h = (nt16&3)*16+l16].
// A wave's B-frag load becomes one contiguous 1KB read.
// ---------------------------------------------------------------------------
__global__ void wt_kernel(const float* __restrict__ Wq, const float* __restrict__ Wk,
                          const float* __restrict__ Wv, short* __restrict__ wt2) {
    int idx = blockIdx.x * 256 + threadIdx.x;
    if (idx >= 12 * 12 * 512) return;
    int f = idx >> 9, within = idx & 511;
    int lane = within >> 3, jj = within & 7;
    int nt16 = f / 12, kc32 = f - nt16 * 12;
    int mat = nt16 >> 2, w = nt16 & 3;
    int quad = lane >> 4, l16 = lane & 15;
    int h = w * 16 + l16;
    int c = kc32 * 32 + quad * 8 + jj;
    const float* W = (mat == 0) ? Wq : ((mat == 1) ? Wk : Wv);
    wt2[idx] = f2bf(W[c * H_ + h]);
}

// ---------------------------------------------------------------------------
// Kernel 1: QKV projection, 32-row tiles (1024 blocks -> ~6 blocks/CU).
// B-frags from pre-swizzled wt2 (coalesced). Epilogue staged via LDS.
// ---------------------------------------------------------------------------
__global__ __launch_bounds__(256) void qkv_kernel(
        const float* __restrict__ x, const short* __restrict__ wt2,
        short* __restrict__ qo, short* __restrict__ ko, short* __restrict__ vto) {
    __shared__ short xs[32 * 392];   // 24.5 KB; reused for out staging (7.7K shorts)

    int b = blockIdx.y, t0 = blockIdx.x * 32;
    int tid = threadIdx.x;

    const float* src = x + (size_t)(b * T_ + t0) * C_;
    for (int i = 0; i < 12; i++) {
        int chunk = i * 256 + tid;              // 3072 chunks of 4 floats
        int row = chunk / 96, off = (chunk % 96) * 4;
        float4 f = *(const float4*)&src[row * 384 + off];
        short4_t s4;
        s4.x = f2bf(f.x); s4.y = f2bf(f.y); s4.z = f2bf(f.z); s4.w = f2bf(f.w);
        *(short4_t*)&xs[row * 392 + off] = s4;
    }
    __syncthreads();

    int w = tid >> 6, lane = tid & 63, quad = lane >> 4, l16 = lane & 15;

    floatx4 acc[2][3];
    for (int mt = 0; mt < 2; mt++)
        for (int j = 0; j < 3; j++) acc[mt][j] = (floatx4)0.0f;

    for (int kc = 0; kc < 384; kc += 32) {
        int kc32 = kc >> 5;
        short8 a0 = *(const short8*)&xs[l16 * 392 + kc + quad * 8];
        short8 a1 = *(const short8*)&xs[(16 + l16) * 392 + kc + quad * 8];
        for (int j = 0; j < 3; j++) {
            short8 bf = *(const short8*)&wt2[(((j * 4 + w) * 12) + kc32) * 512 + lane * 8];
            acc[0][j] = __builtin_amdgcn_mfma_f32_16x16x32_bf16(a0, bf, acc[0][j], 0, 0, 0);
            acc[1][j] = __builtin_amdgcn_mfma_f32_16x16x32_bf16(a1, bf, acc[1][j], 0, 0, 0);
        }
    }
    __syncthreads();   // xs reads done; reuse as staging

    {
        int h = w * 16 + l16;
        for (int j = 0; j < 3; j++)
            for (int mt = 0; mt < 2; mt++)
                for (int r = 0; r < 4; r++) {
                    int tl = mt * 16 + quad * 4 + r;
                    short bv = f2bf(acc[mt][j][r]);
                    if (j == 0)      xs[tl * 72 + h] = bv;
                    else if (j == 1) xs[2304 + tl * 72 + h] = bv;
                    else             xs[4608 + h * 40 + tl] = bv;
                }
    }
    __syncthreads();

    {   // q,k: 32 rows x 64 cols, one short8 per thread each
        int row = tid >> 3, off = (tid & 7) * 8;
        *(short8*)&qo[(size_t)(b * T_ + t0 + row) * H_ + off] = *(const short8*)&xs[row * 72 + off];
        *(short8*)&ko[(size_t)(b * T_ + t0 + row) * H_ + off] = *(const short8*)&xs[2304 + row * 72 + off];
    }
    {   // vt: 64 rows(h) x 32 cols
        int h = tid >> 2, off = (tid & 3) * 8;
        *(short8*)&vto[(size_t)(b * H_ + h) * T_ + t0 + off] = *(const short8*)&xs[4608 + h * 40 + off];
    }
}

// ---------------------------------------------------------------------------
// Kernel 2a: split-K attention, 128 q-rows/block (2 m-tiles/wave), LDS K/V.
// Slot = unnormalized O [128][64] fp32 + l [128].
// ---------------------------------------------------------------------------
__global__ __launch_bounds__(256) void attn_seg_kernel(
        const short* __restrict__ q, const short* __restrict__ k,
        const short* __restrict__ vt, float* __restrict__ slots) {
    __shared__ short ks[64 * 72];
    __shared__ short vs[64 * 72];
    __shared__ short ps[128 * 72];

    int b = blockIdx.y, fid = blockIdx.x, nslot = gridDim.x;
    int tt = 0, cum = 0;                         // tt: 128-row q-tile index
    while (cum + ((2 * tt + 5) >> 2) <= fid) { cum += (2 * tt + 5) >> 2; tt++; }
    int nk = 2 * tt + 2;                         // 64-key tiles needed
    int k0 = (fid - cum) * 4;
    int k1 = min(k0 + 4, nk);

    int tid = threadIdx.x, w = tid >> 6, lane = tid & 63, quad = lane >> 4, l16 = lane & 15;
    int trow0 = tt * 128 + w * 32;               // this wave's first q-row

    short8 aq[2][2];
    for (int mt = 0; mt < 2; mt++) {
        const short* qrow = q + (size_t)(b * T_ + trow0 + mt * 16 + l16) * H_;
        aq[mt][0] = *(const short8*)&qrow[quad * 8];
        aq[mt][1] = *(const short8*)&qrow[32 + quad * 8];
    }

    floatx4 o[2][4];
    float lp[2][4];
    for (int mt = 0; mt < 2; mt++)
        for (int i = 0; i < 4; i++) { o[mt][i] = (floatx4)0.0f; lp[mt][i] = 0.f; }

    const short* kb0 = k + (size_t)b * T_ * H_;
    const short* vtb = vt + (size_t)b * H_ * T_;
    short* psw = ps + w * 32 * 72;

    int srow = tid >> 3, soff = (tid & 7) * 8;
    const float C1 = 0.125f * 1.44269504f;
    const float C2 = 12.0f * 1.44269504f;

    for (int st = k0; st < k1; st++) {
        int s0 = st * 64;
        const short* kg = kb0 + (size_t)s0 * H_;
        const short* vg = vtb + s0;
        *(short8*)&ks[srow * 72 + soff]        = *(const short8*)&kg[srow * H_ + soff];
        *(short8*)&ks[(srow + 32) * 72 + soff] = *(const short8*)&kg[(srow + 32) * H_ + soff];
        *(short8*)&vs[srow * 72 + soff]        = *(const short8*)&vg[(size_t)srow * T_ + soff];
        *(short8*)&vs[(srow + 32) * 72 + soff] = *(const short8*)&vg[(size_t)(srow + 32) * T_ + soff];
        __syncthreads();

        floatx4 sacc[2][4];
        for (int mt = 0; mt < 2; mt++)
            for (int nt = 0; nt < 4; nt++) sacc[mt][nt] = (floatx4)0.0f;
        for (int nt = 0; nt < 4; nt++) {
            short8 bk0 = *(const short8*)&ks[(nt * 16 + l16) * 72 + quad * 8];
            short8 bk1 = *(const short8*)&ks[(nt * 16 + l16) * 72 + 32 + quad * 8];
            sacc[0][nt] = __builtin_amdgcn_mfma_f32_16x16x32_bf16(aq[0][0], bk0, sacc[0][nt], 0, 0, 0);
            sacc[0][nt] = __builtin_amdgcn_mfma_f32_16x16x32_bf16(aq[0][1], bk1, sacc[0][nt], 0, 0, 0);
            sacc[1][nt] = __builtin_amdgcn_mfma_f32_16x16x32_bf16(aq[1][0], bk0, sacc[1][nt], 0, 0, 0);
            sacc[1][nt] = __builtin_amdgcn_mfma_f32_16x16x32_bf16(aq[1][1], bk1, sacc[1][nt], 0, 0, 0);
        }

        bool diag = (st >= 2 * tt);
        for (int mt = 0; mt < 2; mt++)
            for (int nt = 0; nt < 4; nt++) {
                int s_idx = s0 + nt * 16 + l16;
                for (int r = 0; r < 4; r++) {
                    float p = exp2f(fmaf(sacc[mt][nt][r], C1, -C2));
                    if (diag && (s_idx > trow0 + mt * 16 + quad * 4 + r)) p = 0.0f;
                    lp[mt][r] += p;
                    psw[(mt * 16 + quad * 4 + r) * 72 + nt * 16 + l16] = f2bf(p);
                }
            }

        short8 ap[2][2];
        for (int mt = 0; mt < 2; mt++) {
            ap[mt][0] = *(const short8*)&psw[(mt * 16 + l16) * 72 + quad * 8];
            ap[mt][1] = *(const short8*)&psw[(mt * 16 + l16) * 72 + 32 + quad * 8];
        }
        for (int nh = 0; nh < 4; nh++) {
            short8 bv0 = *(const short8*)&vs[(nh * 16 + l16) * 72 + quad * 8];
            short8 bv1 = *(const short8*)&vs[(nh * 16 + l16) * 72 + 32 + quad * 8];
            o[0][nh] = __builtin_amdgcn_mfma_f32_16x16x32_bf16(ap[0][0], bv0, o[0][nh], 0, 0, 0);
            o[0][nh] = __builtin_amdgcn_mfma_f32_16x16x32_bf16(ap[0][1], bv1, o[0][nh], 0, 0, 0);
            o[1][nh] = __builtin_amdgcn_mfma_f32_16x16x32_bf16(ap[1][0], bv0, o[1][nh], 0, 0, 0);
            o[1][nh] = __builtin_amdgcn_mfma_f32_16x16x32_bf16(ap[1][1], bv1, o[1][nh], 0, 0, 0);
        }
        __syncthreads();
    }

    for (int d = 1; d < 16; d <<= 1)
        for (int mt = 0; mt < 2; mt++)
            for (int r = 0; r < 4; r++)
                lp[mt][r] += __shfl_xor(lp[mt][r], d, 16);

    float* slot = slots + ((size_t)b * nslot + fid) * 8320;   // 8192 O + 128 l
    for (int mt = 0; mt < 2; mt++)
        for (int nh = 0; nh < 4; nh++)
            for (int r = 0; r < 4; r++)
                slot[(w * 32 + mt * 16 + quad * 4 + r) * 64 + nh * 16 + l16] = o[mt][nh][r];
    if (l16 == 0)
        for (int mt = 0; mt < 2; mt++)
            for (int r = 0; r < 4; r++)
                slot[8192 + w * 32 + mt * 16 + quad * 4 + r] = lp[mt][r];
}

// ---------------------------------------------------------------------------
// Kernel 2b: combine. Block = (tt, b), 128 rows. Sum slots, normalize, write.
// ---------------------------------------------------------------------------
__global__ __launch_bounds__(256) void combine_kernel(
        const float* __restrict__ slots, int nslot, float* __restrict__ out) {
    int b = blockIdx.y, tt = blockIdx.x;
    int nseg = (2 * tt + 5) >> 2;
    int cum = 0;
    for (int i = 0; i < tt; i++) cum += (2 * i + 5) >> 2;
    const float* base = slots + ((size_t)b * nslot + cum) * 8320;

    int tid = threadIdx.x;
    int row = tid >> 1, c0 = (tid & 1) * 32;
    float4 acc[8] = {};
    float lsum = 0.f;
    for (int s = 0; s < nseg; s++) {
        const float* sp = base + (size_t)s * 8320;
        for (int i = 0; i < 8; i++) {
            float4 v = *(const float4*)&sp[row * 64 + c0 + i * 4];
            acc[i].x += v.x; acc[i].y += v.y; acc[i].z += v.z; acc[i].w += v.w;
        }
        lsum += sp[8192 + row];
    }
    float inv = 1.0f / lsum;
    float* op = out + (size_t)(b * T_ + tt * 128 + row) * H_ + c0;
    for (int i = 0; i < 8; i++) {
        float4 v;
        v.x = acc[i].x * inv; v.y = acc[i].y * inv;
        v.z = acc[i].z * inv; v.w = acc[i].w * inv;
        *(float4*)&op[i * 4] = v;
    }
}

// ---------------------------------------------------------------------------
// Fallback direct attention (64-row, global-gather) — no slot workspace.
// ---------------------------------------------------------------------------
template<bool DIAG>
static __device__ __forceinline__ void attn_step(
        int s0, int t0w, int quad, int l16,
        const short* __restrict__ kbase, const short* __restrict__ vtb,
        short8 aq0, short8 aq1, short* __restrict__ psw,
        floatx4 (&o)[4], float (&lpart)[4]) {
    floatx4 sacc[4];
    for (int nt = 0; nt < 4; nt++) sacc[nt] = (floatx4)0.0f;
    for (int nt = 0; nt < 4; nt++) {
        short8 bk0 = *(const short8*)&kbase[(nt * 16 + l16) * H_ + quad * 8];
        short8 bk1 = *(const short8*)&kbase[(nt * 16 + l16) * H_ + 32 + quad * 8];
        sacc[nt] = __builtin_amdgcn_mfma_f32_16x16x32_bf16(aq0, bk0, sacc[nt], 0, 0, 0);
        sacc[nt] = __builtin_amdgcn_mfma_f32_16x16x32_bf16(aq1, bk1, sacc[nt], 0, 0, 0);
    }
    const float C1 = 0.125f * 1.44269504f;
    const float C2 = 12.0f * 1.44269504f;
    for (int nt = 0; nt < 4; nt++) {
        int s_idx = s0 + nt * 16 + l16;
        for (int r = 0; r < 4; r++) {
            float p = exp2f(fmaf(sacc[nt][r], C1, -C2));
            if (DIAG && (s_idx > t0w + quad * 4 + r)) p = 0.0f;
            lpart[r] += p;
            psw[(quad * 4 + r) * 72 + nt * 16 + l16] = f2bf(p);
        }
    }
    short8 ap0 = *(const short8*)&psw[l16 * 72 + quad * 8];
    short8 ap1 = *(const short8*)&psw[l16 * 72 + 32 + quad * 8];
    for (int nh = 0; nh < 4; nh++) {
        short8 bv0 = *(const short8*)&vtb[(size_t)(nh * 16 + l16) * T_ + s0 + quad * 8];
        short8 bv1 = *(const short8*)&vtb[(size_t)(nh * 16 + l16) * T_ + s0 + 32 + quad * 8];
        o[nh] = __builtin_amdgcn_mfma_f32_16x16x32_bf16(ap0, bv0, o[nh], 0, 0, 0);
        o[nh] = __builtin_amdgcn_mfma_f32_16x16x32_bf16(ap1, bv1, o[nh], 0, 0, 0);
    }
}

__global__ __launch_bounds__(256) void attn_kernel(
        const short* __restrict__ q, const short* __restrict__ k,
        const short* __restrict__ vt, float* __restrict__ out) {
    __shared__ short ps[4 * 16 * 72];

    int b = blockIdx.y;
    int g = ((int)blockIdx.x + 4 * (b & 7)) & 31;
    int tt = (b < 8) ? g : 31 - g;
    int t0 = tt * 64;
    int tid = threadIdx.x, w = tid >> 6, lane = tid & 63, quad = lane >> 4, l16 = lane & 15;
    int t0w = t0 + w * 16;

    const short* qrow = q + (size_t)(b * T_ + t0w + l16) * H_;
    short8 aq0 = *(const short8*)&qrow[quad * 8];
    short8 aq1 = *(const short8*)&qrow[32 + quad * 8];

    floatx4 o[4];
    for (int nh = 0; nh < 4; nh++) o[nh] = (floatx4)0.0f;
    float lpart[4] = {0.f, 0.f, 0.f, 0.f};

    const short* kb0 = k + (size_t)b * T_ * H_;
    const short* vtb = vt + (size_t)b * H_ * T_;
    short* psw = ps + w * 16 * 72;

    for (int st = 0; st < tt; st++)
        attn_step<false>(st * 64, t0w, quad, l16, kb0 + (size_t)st * 64 * H_,
                         vtb, aq0, aq1, psw, o, lpart);
    attn_step<true>(tt * 64, t0w, quad, l16, kb0 + (size_t)tt * 64 * H_,
                    vtb, aq0, aq1, psw, o, lpart);

    for (int d = 1; d < 16; d <<= 1)
        for (int r = 0; r < 4; r++)
            lpart[r] += __shfl_xor(lpart[r], d, 16);

    for (int nh = 0; nh < 4; nh++)
        for (int r = 0; r < 4; r++) {
            int t = t0w + quad * 4 + r;
            out[(size_t)(b * T_ + t) * H_ + nh * 16 + l16] = o[nh][r] / lpart[r];
        }
}

// ---------------------------------------------------------------------------
extern "C" void kernel_launch(void* const* d_in, const int* in_sizes, int n_in,
                              void* d_out, int out_size, void* d_ws, size_t ws_size,
                              hipStream_t stream) {
    const float* x  = (const float*)d_in[0];
    const float* Wq = (const float*)d_in[1];
    const float* Wk = (const float*)d_in[2];
    const float* Wv = (const float*)d_in[3];

    char* ws = (char*)d_ws;
    short* qb  = (short*)(ws);                                  // 4 MB
    short* kb  = (short*)(ws + (size_t)4 * 1024 * 1024);        // 4 MB
    short* vtb = (short*)(ws + (size_t)8 * 1024 * 1024);        // 4 MB, [B][H][T]
    short* wtb = (short*)(ws + (size_t)12 * 1024 * 1024);       // 144 KB (frag order)
    float* slots = (float*)(ws + (size_t)12 * 1024 * 1024 + 256 * 1024);
    size_t base_need = (size_t)12 * 1024 * 1024 + 256 * 1024;

    wt_kernel<<<dim3(288), dim3(256), 0, stream>>>(Wq, Wk, Wv, wtb);
    qkv_kernel<<<dim3(T_ / 32, B_), dim3(256), 0, stream>>>(x, wtb, qb, kb, vtb);

    float* out = (float*)d_out;
    const int NSLOT = 72;   // sum_{tt=0}^{15} ceil((2tt+2)/4)
    if (ws_size >= base_need + (size_t)B_ * NSLOT * 8320 * sizeof(float)) {
        attn_seg_kernel<<<dim3(NSLOT, B_), dim3(256), 0, stream>>>(qb, kb, vtb, slots);
        combine_kernel<<<dim3(T_ / 128, B_), dim3(256), 0, stream>>>(slots, NSLOT, out);
    } else {
        attn_kernel<<<dim3(T_ / 64, B_), dim3(256), 0, stream>>>(qb, kb, vtb, out);
    }
}

// Round 8
// 140.649 us; speedup vs baseline: 1.0189x; 1.0189x over previous
//
#include <hip/hip_runtime.h>
#include <hip/hip_bf16.h>

#define B_ 16
#define T_ 2048
#define C_ 384
#define H_ 64

typedef __attribute__((ext_vector_type(8))) short short8;
typedef __attribute__((ext_vector_type(4))) short short4_t;
typedef __attribute__((ext_vector_type(4))) float floatx4;

static __device__ __forceinline__ short f2bf(float f) {
    unsigned u = __builtin_bit_cast(unsigned, f);
    u += 0x7FFF + ((u >> 16) & 1);   // round-to-nearest-even
    return (short)(u >> 16);
}
static __device__ __forceinline__ float bf2f(short s) {
    return __builtin_bit_cast(float, ((unsigned)(unsigned short)s) << 16);
}

// ---------------------------------------------------------------------------
// Kernel 0: weights fp32[C,H] -> bf16 in MFMA B-fragment order (as R7).
// ---------------------------------------------------------------------------
__global__ void wt_kernel(const float* __restrict__ Wq, const float* __restrict__ Wk,
                          const float* __restrict__ Wv, short* __restrict__ wt2) {
    int idx = blockIdx.x * 256 + threadIdx.x;
    if (idx >= 12 * 12 * 512) return;
    int f = idx >> 9, within = idx & 511;
    int lane = within >> 3, jj = within & 7;
    int nt16 = f / 12, kc32 = f - nt16 * 12;
    int mat = nt16 >> 2, w = nt16 & 3;
    int quad = lane >> 4, l16 = lane & 15;
    int h = w * 16 + l16;
    int c = kc32 * 32 + quad * 8 + jj;
    const float* W = (mat == 0) ? Wq : ((mat == 1) ? Wk : Wv);
    wt2[idx] = f2bf(W[c * H_ + h]);
}

// ---------------------------------------------------------------------------
// Kernel 1: QKV projection (byte-identical to R7 — experiment isolation).
// ---------------------------------------------------------------------------
__global__ __launch_bounds__(256) void qkv_kernel(
        const float* __restrict__ x, const short* __restrict__ wt2,
        short* __restrict__ qo, short* __restrict__ ko, short* __restrict__ vto) {
    __shared__ short xs[32 * 392];

    int b = blockIdx.y, t0 = blockIdx.x * 32;
    int tid = threadIdx.x;

    const float* src = x + (size_t)(b * T_ + t0) * C_;
    for (int i = 0; i < 12; i++) {
        int chunk = i * 256 + tid;
        int row = chunk / 96, off = (chunk % 96) * 4;
        float4 f = *(const float4*)&src[row * 384 + off];
        short4_t s4;
        s4.x = f2bf(f.x); s4.y = f2bf(f.y); s4.z = f2bf(f.z); s4.w = f2bf(f.w);
        *(short4_t*)&xs[row * 392 + off] = s4;
    }
    __syncthreads();

    int w = tid >> 6, lane = tid & 63, quad = lane >> 4, l16 = lane & 15;

    floatx4 acc[2][3];
    for (int mt = 0; mt < 2; mt++)
        for (int j = 0; j < 3; j++) acc[mt][j] = (floatx4)0.0f;

    for (int kc = 0; kc < 384; kc += 32) {
        int kc32 = kc >> 5;
        short8 a0 = *(const short8*)&xs[l16 * 392 + kc + quad * 8];
        short8 a1 = *(const short8*)&xs[(16 + l16) * 392 + kc + quad * 8];
        for (int j = 0; j < 3; j++) {
            short8 bf = *(const short8*)&wt2[(((j * 4 + w) * 12) + kc32) * 512 + lane * 8];
            acc[0][j] = __builtin_amdgcn_mfma_f32_16x16x32_bf16(a0, bf, acc[0][j], 0, 0, 0);
            acc[1][j] = __builtin_amdgcn_mfma_f32_16x16x32_bf16(a1, bf, acc[1][j], 0, 0, 0);
        }
    }
    __syncthreads();

    {
        int h = w * 16 + l16;
        for (int j = 0; j < 3; j++)
            for (int mt = 0; mt < 2; mt++)
                for (int r = 0; r < 4; r++) {
                    int tl = mt * 16 + quad * 4 + r;
                    short bv = f2bf(acc[mt][j][r]);
                    if (j == 0)      xs[tl * 72 + h] = bv;
                    else if (j == 1) xs[2304 + tl * 72 + h] = bv;
                    else             xs[4608 + h * 40 + tl] = bv;
                }
    }
    __syncthreads();

    {
        int row = tid >> 3, off = (tid & 7) * 8;
        *(short8*)&qo[(size_t)(b * T_ + t0 + row) * H_ + off] = *(const short8*)&xs[row * 72 + off];
        *(short8*)&ko[(size_t)(b * T_ + t0 + row) * H_ + off] = *(const short8*)&xs[2304 + row * 72 + off];
    }
    {
        int h = tid >> 2, off = (tid & 3) * 8;
        *(short8*)&vto[(size_t)(b * H_ + h) * T_ + t0 + off] = *(const short8*)&xs[4608 + h * 40 + off];
    }
}

// ---------------------------------------------------------------------------
// Kernel 2a: split-K attention, 128-row q-tiles, double-buffered K/V staging
// (ONE barrier per step), bf16 O slots. Slot = O bf16[128][64] + l fp32[128].
// ---------------------------------------------------------------------------
#define KVSZ (64 * 72)          // one K or V buffer, shorts
#define SLOT_BYTES (16384 + 512)

__global__ __launch_bounds__(256) void attn_seg_kernel(
        const short* __restrict__ q, const short* __restrict__ k,
        const short* __restrict__ vt, float* __restrict__ slots) {
    __shared__ short ks[2 * KVSZ];
    __shared__ short vs[2 * KVSZ];
    __shared__ short ps[4 * 16 * 72];   // one 16-row region per wave

    int b = blockIdx.y, fid = blockIdx.x, nslot = gridDim.x;
    int tt = 0, cum = 0;                         // 128-row q-tile index
    while (cum + ((2 * tt + 5) >> 2) <= fid) { cum += (2 * tt + 5) >> 2; tt++; }
    int nk = 2 * tt + 2;
    int k0 = (fid - cum) * 4;
    int k1 = min(k0 + 4, nk);

    int tid = threadIdx.x, w = tid >> 6, lane = tid & 63, quad = lane >> 4, l16 = lane & 15;
    int trow0 = tt * 128 + w * 32;

    short8 aq[2][2];
    for (int mt = 0; mt < 2; mt++) {
        const short* qrow = q + (size_t)(b * T_ + trow0 + mt * 16 + l16) * H_;
        aq[mt][0] = *(const short8*)&qrow[quad * 8];
        aq[mt][1] = *(const short8*)&qrow[32 + quad * 8];
    }

    floatx4 o[2][4];
    float lp[2][4];
    for (int mt = 0; mt < 2; mt++)
        for (int i = 0; i < 4; i++) { o[mt][i] = (floatx4)0.0f; lp[mt][i] = 0.f; }

    const short* kb0 = k + (size_t)b * T_ * H_;
    const short* vtb = vt + (size_t)b * H_ * T_;
    short* psw = ps + w * 16 * 72;

    int srow = tid >> 3, soff = (tid & 7) * 8;
    const float C1 = 0.125f * 1.44269504f;
    const float C2 = 12.0f * 1.44269504f;

    // preload first tile into buffer 0
    {
        const short* kg = kb0 + (size_t)k0 * 64 * H_;
        const short* vg = vtb + k0 * 64;
        short8 a = *(const short8*)&kg[srow * H_ + soff];
        short8 c = *(const short8*)&kg[(srow + 32) * H_ + soff];
        short8 d = *(const short8*)&vg[(size_t)srow * T_ + soff];
        short8 e = *(const short8*)&vg[(size_t)(srow + 32) * T_ + soff];
        *(short8*)&ks[srow * 72 + soff] = a;
        *(short8*)&ks[(srow + 32) * 72 + soff] = c;
        *(short8*)&vs[srow * 72 + soff] = d;
        *(short8*)&vs[(srow + 32) * 72 + soff] = e;
    }
    __syncthreads();

    int p = 0;
    for (int st = k0; st < k1; st++) {
        bool more = (st + 1 < k1);
        short8 pk0, pk1, pv0, pv1;
        if (more) {   // prefetch next tile into registers (latency hidden by compute)
            const short* kg = kb0 + (size_t)(st + 1) * 64 * H_;
            const short* vg = vtb + (st + 1) * 64;
            pk0 = *(const short8*)&kg[srow * H_ + soff];
            pk1 = *(const short8*)&kg[(srow + 32) * H_ + soff];
            pv0 = *(const short8*)&vg[(size_t)srow * T_ + soff];
            pv1 = *(const short8*)&vg[(size_t)(srow + 32) * T_ + soff];
        }
        const short* ksp = ks + p * KVSZ;
        const short* vsp = vs + p * KVSZ;
        int s0 = st * 64;

        // S = Q K^T for both m-tiles
        floatx4 sacc[2][4];
        for (int mt = 0; mt < 2; mt++)
            for (int nt = 0; nt < 4; nt++) sacc[mt][nt] = (floatx4)0.0f;
        for (int nt = 0; nt < 4; nt++) {
            short8 bk0 = *(const short8*)&ksp[(nt * 16 + l16) * 72 + quad * 8];
            short8 bk1 = *(const short8*)&ksp[(nt * 16 + l16) * 72 + 32 + quad * 8];
            sacc[0][nt] = __builtin_amdgcn_mfma_f32_16x16x32_bf16(aq[0][0], bk0, sacc[0][nt], 0, 0, 0);
            sacc[0][nt] = __builtin_amdgcn_mfma_f32_16x16x32_bf16(aq[0][1], bk1, sacc[0][nt], 0, 0, 0);
            sacc[1][nt] = __builtin_amdgcn_mfma_f32_16x16x32_bf16(aq[1][0], bk0, sacc[1][nt], 0, 0, 0);
            sacc[1][nt] = __builtin_amdgcn_mfma_f32_16x16x32_bf16(aq[1][1], bk1, sacc[1][nt], 0, 0, 0);
        }

        // fixed-cap softmax numerator + causal mask
        bool diag = (st >= 2 * tt);
        for (int mt = 0; mt < 2; mt++)
            for (int nt = 0; nt < 4; nt++) {
                int s_idx = s0 + nt * 16 + l16;
                for (int r = 0; r < 4; r++) {
                    float pv = exp2f(fmaf(sacc[mt][nt][r], C1, -C2));
                    if (diag && (s_idx > trow0 + mt * 16 + quad * 4 + r)) pv = 0.0f;
                    lp[mt][r] += pv;
                    sacc[mt][nt][r] = pv;
                }
            }

        // P: C-layout -> A-layout via per-wave 16-row LDS region, mt sequential
        short8 ap[2][2];
        for (int mt = 0; mt < 2; mt++) {
            for (int nt = 0; nt < 4; nt++)
                for (int r = 0; r < 4; r++)
                    psw[(quad * 4 + r) * 72 + nt * 16 + l16] = f2bf(sacc[mt][nt][r]);
            ap[mt][0] = *(const short8*)&psw[l16 * 72 + quad * 8];
            ap[mt][1] = *(const short8*)&psw[l16 * 72 + 32 + quad * 8];
        }

        // O += P V (V-frags shared across both m-tiles)
        for (int nh = 0; nh < 4; nh++) {
            short8 bv0 = *(const short8*)&vsp[(nh * 16 + l16) * 72 + quad * 8];
            short8 bv1 = *(const short8*)&vsp[(nh * 16 + l16) * 72 + 32 + quad * 8];
            o[0][nh] = __builtin_amdgcn_mfma_f32_16x16x32_bf16(ap[0][0], bv0, o[0][nh], 0, 0, 0);
            o[0][nh] = __builtin_amdgcn_mfma_f32_16x16x32_bf16(ap[0][1], bv1, o[0][nh], 0, 0, 0);
            o[1][nh] = __builtin_amdgcn_mfma_f32_16x16x32_bf16(ap[1][0], bv0, o[1][nh], 0, 0, 0);
            o[1][nh] = __builtin_amdgcn_mfma_f32_16x16x32_bf16(ap[1][1], bv1, o[1][nh], 0, 0, 0);
        }

        if (more) {   // write prefetched tile to the other buffer; ONE barrier
            short* kd = ks + (1 - p) * KVSZ;
            short* vd = vs + (1 - p) * KVSZ;
            *(short8*)&kd[srow * 72 + soff] = pk0;
            *(short8*)&kd[(srow + 32) * 72 + soff] = pk1;
            *(short8*)&vd[srow * 72 + soff] = pv0;
            *(short8*)&vd[(srow + 32) * 72 + soff] = pv1;
            __syncthreads();
            p ^= 1;
        }
    }

    for (int d = 1; d < 16; d <<= 1)
        for (int mt = 0; mt < 2; mt++)
            for (int r = 0; r < 4; r++)
                lp[mt][r] += __shfl_xor(lp[mt][r], d, 16);

    char* slotb = (char*)slots + ((size_t)b * nslot + fid) * SLOT_BYTES;
    short* slotO = (short*)slotb;
    float* slotL = (float*)(slotb + 16384);

    // O -> bf16 [q][h] via per-wave ps region (mt sequential), coalesced stores
    for (int mt = 0; mt < 2; mt++) {
        for (int nh = 0; nh < 4; nh++)
            for (int r = 0; r < 4; r++)
                psw[(quad * 4 + r) * 72 + nh * 16 + l16] = f2bf(o[mt][nh][r]);
        for (int it = 0; it < 2; it++) {
            int u = it * 64 + lane;          // 128 short8 units = 16 rows x 64
            int row = u >> 3, seg = u & 7;
            *(short8*)&slotO[(w * 32 + mt * 16 + row) * 64 + seg * 8] =
                *(const short8*)&psw[row * 72 + seg * 8];
        }
    }
    if (l16 == 0)
        for (int mt = 0; mt < 2; mt++)
            for (int r = 0; r < 4; r++)
                slotL[w * 32 + mt * 16 + quad * 4 + r] = lp[mt][r];
}

// ---------------------------------------------------------------------------
// Kernel 2b: combine. Block = (tt, b), 128 rows; bf16 slot O, fp32 l.
// ---------------------------------------------------------------------------
__global__ __launch_bounds__(256) void combine_kernel(
        const float* __restrict__ slots, int nslot, float* __restrict__ out) {
    int b = blockIdx.y, tt = blockIdx.x;
    int nseg = (2 * tt + 5) >> 2;
    int cum = 0;
    for (int i = 0; i < tt; i++) cum += (2 * i + 5) >> 2;
    const char* base = (const char*)slots + ((size_t)b * nslot + cum) * SLOT_BYTES;

    int tid = threadIdx.x;
    int row = tid >> 1, half = tid & 1;
    float acc[32];
    for (int i = 0; i < 32; i++) acc[i] = 0.f;
    float lsum = 0.f;
    for (int s = 0; s < nseg; s++) {
        const short* O = (const short*)(base + (size_t)s * SLOT_BYTES);
        const float* L = (const float*)(base + (size_t)s * SLOT_BYTES + 16384);
        for (int i = 0; i < 4; i++) {
            short8 v = *(const short8*)&O[row * 64 + half * 32 + i * 8];
            for (int j = 0; j < 8; j++) acc[i * 8 + j] += bf2f(v[j]);
        }
        lsum += L[row];
    }
    float inv = 1.0f / lsum;
    float* op = out + (size_t)(b * T_ + tt * 128 + row) * H_ + half * 32;
    for (int i = 0; i < 8; i++) {
        float4 v;
        v.x = acc[i * 4 + 0] * inv; v.y = acc[i * 4 + 1] * inv;
        v.z = acc[i * 4 + 2] * inv; v.w = acc[i * 4 + 3] * inv;
        *(float4*)&op[i * 4] = v;
    }
}

// ---------------------------------------------------------------------------
// Fallback direct attention (unchanged; used only if ws too small).
// ---------------------------------------------------------------------------
template<bool DIAG>
static __device__ __forceinline__ void attn_step(
        int s0, int t0w, int quad, int l16,
        const short* __restrict__ kbase, const short* __restrict__ vtb,
        short8 aq0, short8 aq1, short* __restrict__ psw,
        floatx4 (&o)[4], float (&lpart)[4]) {
    floatx4 sacc[4];
    for (int nt = 0; nt < 4; nt++) sacc[nt] = (floatx4)0.0f;
    for (int nt = 0; nt < 4; nt++) {
        short8 bk0 = *(const short8*)&kbase[(nt * 16 + l16) * H_ + quad * 8];
        short8 bk1 = *(const short8*)&kbase[(nt * 16 + l16) * H_ + 32 + quad * 8];
        sacc[nt] = __builtin_amdgcn_mfma_f32_16x16x32_bf16(aq0, bk0, sacc[nt], 0, 0, 0);
        sacc[nt] = __builtin_amdgcn_mfma_f32_16x16x32_bf16(aq1, bk1, sacc[nt], 0, 0, 0);
    }
    const float C1 = 0.125f * 1.44269504f;
    const float C2 = 12.0f * 1.44269504f;
    for (int nt = 0; nt < 4; nt++) {
        int s_idx = s0 + nt * 16 + l16;
        for (int r = 0; r < 4; r++) {
            float p = exp2f(fmaf(sacc[nt][r], C1, -C2));
            if (DIAG && (s_idx > t0w + quad * 4 + r)) p = 0.0f;
            lpart[r] += p;
            psw[(quad * 4 + r) * 72 + nt * 16 + l16] = f2bf(p);
        }
    }
    short8 ap0 = *(const short8*)&psw[l16 * 72 + quad * 8];
    short8 ap1 = *(const short8*)&psw[l16 * 72 + 32 + quad * 8];
    for (int nh = 0; nh < 4; nh++) {
        short8 bv0 = *(const short8*)&vtb[(size_t)(nh * 16 + l16) * T_ + s0 + quad * 8];
        short8 bv1 = *(const short8*)&vtb[(size_t)(nh * 16 + l16) * T_ + s0 + 32 + quad * 8];
        o[nh] = __builtin_amdgcn_mfma_f32_16x16x32_bf16(ap0, bv0, o[nh], 0, 0, 0);
        o[nh] = __builtin_amdgcn_mfma_f32_16x16x32_bf16(ap1, bv1, o[nh], 0, 0, 0);
    }
}

__global__ __launch_bounds__(256) void attn_kernel(
        const short* __restrict__ q, const short* __restrict__ k,
        const short* __restrict__ vt, float* __restrict__ out) {
    __shared__ short ps[4 * 16 * 72];

    int b = blockIdx.y;
    int g = ((int)blockIdx.x + 4 * (b & 7)) & 31;
    int tt = (b < 8) ? g : 31 - g;
    int t0 = tt * 64;
    int tid = threadIdx.x, w = tid >> 6, lane = tid & 63, quad = lane >> 4, l16 = lane & 15;
    int t0w = t0 + w * 16;

    const short* qrow = q + (size_t)(b * T_ + t0w + l16) * H_;
    short8 aq0 = *(const short8*)&qrow[quad * 8];
    short8 aq1 = *(const short8*)&qrow[32 + quad * 8];

    floatx4 o[4];
    for (int nh = 0; nh < 4; nh++) o[nh] = (floatx4)0.0f;
    float lpart[4] = {0.f, 0.f, 0.f, 0.f};

    const short* kb0 = k + (size_t)b * T_ * H_;
    const short* vtb = vt + (size_t)b * H_ * T_;
    short* psw = ps + w * 16 * 72;

    for (int st = 0; st < tt; st++)
        attn_step<false>(st * 64, t0w, quad, l16, kb0 + (size_t)st * 64 * H_,
                         vtb, aq0, aq1, psw, o, lpart);
    attn_step<true>(tt * 64, t0w, quad, l16, kb0 + (size_t)tt * 64 * H_,
                    vtb, aq0, aq1, psw, o, lpart);

    for (int d = 1; d < 16; d <<= 1)
        for (int r = 0; r < 4; r++)
            lpart[r] += __shfl_xor(lpart[r], d, 16);

    for (int nh = 0; nh < 4; nh++)
        for (int r = 0; r < 4; r++) {
            int t = t0w + quad * 4 + r;
            out[(size_t)(b * T_ + t) * H_ + nh * 16 + l16] = o[nh][r] / lpart[r];
        }
}

// ---------------------------------------------------------------------------
extern "C" void kernel_launch(void* const* d_in, const int* in_sizes, int n_in,
                              void* d_out, int out_size, void* d_ws, size_t ws_size,
                              hipStream_t stream) {
    const float* x  = (const float*)d_in[0];
    const float* Wq = (const float*)d_in[1];
    const float* Wk = (const float*)d_in[2];
    const float* Wv = (const float*)d_in[3];

    char* ws = (char*)d_ws;
    short* qb  = (short*)(ws);                                  // 4 MB
    short* kb  = (short*)(ws + (size_t)4 * 1024 * 1024);        // 4 MB
    short* vtb = (short*)(ws + (size_t)8 * 1024 * 1024);        // 4 MB, [B][H][T]
    short* wtb = (short*)(ws + (size_t)12 * 1024 * 1024);       // 144 KB (frag order)
    float* slots = (float*)(ws + (size_t)12 * 1024 * 1024 + 256 * 1024);
    size_t base_need = (size_t)12 * 1024 * 1024 + 256 * 1024;

    wt_kernel<<<dim3(288), dim3(256), 0, stream>>>(Wq, Wk, Wv, wtb);
    qkv_kernel<<<dim3(T_ / 32, B_), dim3(256), 0, stream>>>(x, wtb, qb, kb, vtb);

    float* out = (float*)d_out;
    const int NSLOT = 72;   // sum_{tt=0}^{15} ceil((2tt+2)/4)
    if (ws_size >= base_need + (size_t)B_ * NSLOT * (size_t)SLOT_BYTES) {
        attn_seg_kernel<<<dim3(NSLOT, B_), dim3(256), 0, stream>>>(qb, kb, vtb, slots);
        combine_kernel<<<dim3(T_ / 128, B_), dim3(256), 0, stream>>>(slots, NSLOT, out);
    } else {
        attn_kernel<<<dim3(T_ / 64, B_), dim3(256), 0, stream>>>(qb, kb, vtb, out);
    }
}

// Round 9
// 138.926 us; speedup vs baseline: 1.0315x; 1.0124x over previous
//
#include <hip/hip_runtime.h>
#include <hip/hip_bf16.h>

#define B_ 16
#define T_ 2048
#define C_ 384
#define H_ 64

typedef __attribute__((ext_vector_type(8))) short short8;
typedef __attribute__((ext_vector_type(4))) short short4_t;
typedef __attribute__((ext_vector_type(4))) float floatx4;

#if defined(__has_builtin)
#if __has_builtin(__builtin_amdgcn_mfma_f32_16x16x16bf16_1k)
#define HAVE_MFMA16 1
#endif
#endif

static __device__ __forceinline__ short f2bf(float f) {
    unsigned u = __builtin_bit_cast(unsigned, f);
    u += 0x7FFF + ((u >> 16) & 1);   // round-to-nearest-even
    return (short)(u >> 16);
}
static __device__ __forceinline__ float bf2f(short s) {
    return __builtin_bit_cast(float, ((unsigned)(unsigned short)s) << 16);
}

// ---------------------------------------------------------------------------
// Kernel 0: weights fp32[C,H] -> bf16 in MFMA B-fragment order (as R7/R8).
// ---------------------------------------------------------------------------
__global__ void wt_kernel(const float* __restrict__ Wq, const float* __restrict__ Wk,
                          const float* __restrict__ Wv, short* __restrict__ wt2) {
    int idx = blockIdx.x * 256 + threadIdx.x;
    if (idx >= 12 * 12 * 512) return;
    int f = idx >> 9, within = idx & 511;
    int lane = within >> 3, jj = within & 7;
    int nt16 = f / 12, kc32 = f - nt16 * 12;
    int mat = nt16 >> 2, w = nt16 & 3;
    int quad = lane >> 4, l16 = lane & 15;
    int h = w * 16 + l16;
    int c = kc32 * 32 + quad * 8 + jj;
    const float* W = (mat == 0) ? Wq : ((mat == 1) ? Wk : Wv);
    wt2[idx] = f2bf(W[c * H_ + h]);
}

// ---------------------------------------------------------------------------
// Kernel 1: QKV projection (byte-identical to R7/R8 — experiment isolation).
// ---------------------------------------------------------------------------
__global__ __launch_bounds__(256) void qkv_kernel(
        const float* __restrict__ x, const short* __restrict__ wt2,
        short* __restrict__ qo, short* __restrict__ ko, short* __restrict__ vto) {
    __shared__ short xs[32 * 392];

    int b = blockIdx.y, t0 = blockIdx.x * 32;
    int tid = threadIdx.x;

    const float* src = x + (size_t)(b * T_ + t0) * C_;
    for (int i = 0; i < 12; i++) {
        int chunk = i * 256 + tid;
        int row = chunk / 96, off = (chunk % 96) * 4;
        float4 f = *(const float4*)&src[row * 384 + off];
        short4_t s4;
        s4.x = f2bf(f.x); s4.y = f2bf(f.y); s4.z = f2bf(f.z); s4.w = f2bf(f.w);
        *(short4_t*)&xs[row * 392 + off] = s4;
    }
    __syncthreads();

    int w = tid >> 6, lane = tid & 63, quad = lane >> 4, l16 = lane & 15;

    floatx4 acc[2][3];
    for (int mt = 0; mt < 2; mt++)
        for (int j = 0; j < 3; j++) acc[mt][j] = (floatx4)0.0f;

    for (int kc = 0; kc < 384; kc += 32) {
        int kc32 = kc >> 5;
        short8 a0 = *(const short8*)&xs[l16 * 392 + kc + quad * 8];
        short8 a1 = *(const short8*)&xs[(16 + l16) * 392 + kc + quad * 8];
        for (int j = 0; j < 3; j++) {
            short8 bf = *(const short8*)&wt2[(((j * 4 + w) * 12) + kc32) * 512 + lane * 8];
            acc[0][j] = __builtin_amdgcn_mfma_f32_16x16x32_bf16(a0, bf, acc[0][j], 0, 0, 0);
            acc[1][j] = __builtin_amdgcn_mfma_f32_16x16x32_bf16(a1, bf, acc[1][j], 0, 0, 0);
        }
    }
    __syncthreads();

    {
        int h = w * 16 + l16;
        for (int j = 0; j < 3; j++)
            for (int mt = 0; mt < 2; mt++)
                for (int r = 0; r < 4; r++) {
                    int tl = mt * 16 + quad * 4 + r;
                    short bv = f2bf(acc[mt][j][r]);
                    if (j == 0)      xs[tl * 72 + h] = bv;
                    else if (j == 1) xs[2304 + tl * 72 + h] = bv;
                    else             xs[4608 + h * 40 + tl] = bv;
                }
    }
    __syncthreads();

    {
        int row = tid >> 3, off = (tid & 7) * 8;
        *(short8*)&qo[(size_t)(b * T_ + t0 + row) * H_ + off] = *(const short8*)&xs[row * 72 + off];
        *(short8*)&ko[(size_t)(b * T_ + t0 + row) * H_ + off] = *(const short8*)&xs[2304 + row * 72 + off];
    }
    {
        int h = tid >> 2, off = (tid & 3) * 8;
        *(short8*)&vto[(size_t)(b * H_ + h) * T_ + t0 + off] = *(const short8*)&xs[4608 + h * 40 + off];
    }
}

// ---------------------------------------------------------------------------
// Kernel 2a: split-K attention, 128-row q-tiles, double-buffered K/V staging.
// S computed TRANSPOSED (S^T = K·Q^T) so P's C-layout registers are exactly
// the A-fragment of mfma_16x16x16 for PV — no LDS round-trip for P.
// Slot = O bf16[128][64] + l fp32[128].
// ---------------------------------------------------------------------------
#define KVSZ (64 * 72)
#define SLOT_BYTES (16384 + 512)

__global__ __launch_bounds__(256) void attn_seg_kernel(
        const short* __restrict__ q, const short* __restrict__ k,
        const short* __restrict__ vt, float* __restrict__ slots) {
    __shared__ short ks[2 * KVSZ];
    __shared__ short vs[2 * KVSZ];
#if !defined(HAVE_MFMA16)
    __shared__ short ps[4 * 16 * 72];
#endif

    int b = blockIdx.y, fid = blockIdx.x, nslot = gridDim.x;
    int tt = 0, cum = 0;
    while (cum + ((2 * tt + 5) >> 2) <= fid) { cum += (2 * tt + 5) >> 2; tt++; }
    int nk = 2 * tt + 2;
    int k0 = (fid - cum) * 4;
    int k1 = min(k0 + 4, nk);

    int tid = threadIdx.x, w = tid >> 6, lane = tid & 63, quad = lane >> 4, l16 = lane & 15;
    int trow0 = tt * 128 + w * 32;

    short8 aq[2][2];
    for (int mt = 0; mt < 2; mt++) {
        const short* qrow = q + (size_t)(b * T_ + trow0 + mt * 16 + l16) * H_;
        aq[mt][0] = *(const short8*)&qrow[quad * 8];
        aq[mt][1] = *(const short8*)&qrow[32 + quad * 8];
    }

    floatx4 o[2][4];
    for (int mt = 0; mt < 2; mt++)
        for (int i = 0; i < 4; i++) o[mt][i] = (floatx4)0.0f;
    float lp[2] = {0.f, 0.f};

    const short* kb0 = k + (size_t)b * T_ * H_;
    const short* vtb = vt + (size_t)b * H_ * T_;

    int srow = tid >> 3, soff = (tid & 7) * 8;
    const float C1 = 0.125f * 1.44269504f;
    const float C2 = 12.0f * 1.44269504f;

    {   // preload first tile into buffer 0
        const short* kg = kb0 + (size_t)k0 * 64 * H_;
        const short* vg = vtb + k0 * 64;
        *(short8*)&ks[srow * 72 + soff] = *(const short8*)&kg[srow * H_ + soff];
        *(short8*)&ks[(srow + 32) * 72 + soff] = *(const short8*)&kg[(srow + 32) * H_ + soff];
        *(short8*)&vs[srow * 72 + soff] = *(const short8*)&vg[(size_t)srow * T_ + soff];
        *(short8*)&vs[(srow + 32) * 72 + soff] = *(const short8*)&vg[(size_t)(srow + 32) * T_ + soff];
    }
    __syncthreads();

    int p = 0;
    for (int st = k0; st < k1; st++) {
        bool more = (st + 1 < k1);
        short8 pk0, pk1, pv0, pv1;
        if (more) {
            const short* kg = kb0 + (size_t)(st + 1) * 64 * H_;
            const short* vg = vtb + (st + 1) * 64;
            pk0 = *(const short8*)&kg[srow * H_ + soff];
            pk1 = *(const short8*)&kg[(srow + 32) * H_ + soff];
            pv0 = *(const short8*)&vg[(size_t)srow * T_ + soff];
            pv1 = *(const short8*)&vg[(size_t)(srow + 32) * T_ + soff];
        }
        const short* ksp = ks + p * KVSZ;
        const short* vsp = vs + p * KVSZ;
        int s0 = st * 64;

        // S^T = K·Q^T : A = K-frag, B = Q-frag (operand swap). C-layout:
        // col(l16) = q, row(quad*4+r) = s-within-16-tile.
        floatx4 sacc[2][4];
        for (int mt = 0; mt < 2; mt++)
            for (int nt = 0; nt < 4; nt++) sacc[mt][nt] = (floatx4)0.0f;
        for (int nt = 0; nt < 4; nt++) {
            short8 bk0 = *(const short8*)&ksp[(nt * 16 + l16) * 72 + quad * 8];
            short8 bk1 = *(const short8*)&ksp[(nt * 16 + l16) * 72 + 32 + quad * 8];
            sacc[0][nt] = __builtin_amdgcn_mfma_f32_16x16x32_bf16(bk0, aq[0][0], sacc[0][nt], 0, 0, 0);
            sacc[0][nt] = __builtin_amdgcn_mfma_f32_16x16x32_bf16(bk1, aq[0][1], sacc[0][nt], 0, 0, 0);
            sacc[1][nt] = __builtin_amdgcn_mfma_f32_16x16x32_bf16(bk0, aq[1][0], sacc[1][nt], 0, 0, 0);
            sacc[1][nt] = __builtin_amdgcn_mfma_f32_16x16x32_bf16(bk1, aq[1][1], sacc[1][nt], 0, 0, 0);
        }

        bool diag = (st >= 2 * tt);
#if defined(HAVE_MFMA16)
        short4_t pa[2][4];
        for (int mt = 0; mt < 2; mt++) {
            int q_idx = trow0 + mt * 16 + l16;
            for (int nt = 0; nt < 4; nt++) {
                short4_t pk;
                for (int r = 0; r < 4; r++) {
                    float pv = exp2f(fmaf(sacc[mt][nt][r], C1, -C2));
                    int s_idx = s0 + nt * 16 + quad * 4 + r;
                    if (diag && (s_idx > q_idx)) pv = 0.0f;
                    lp[mt] += pv;
                    pk[r] = f2bf(pv);
                }
                pa[mt][nt] = pk;
            }
        }
        // O += P·V : A = P (registers!), B = V-frag from vs[h][s], K=16 MFMA.
        for (int nh = 0; nh < 4; nh++) {
            const short* vrow = &vsp[(nh * 16 + l16) * 72 + quad * 4];
            for (int c = 0; c < 4; c++) {
                short4_t bv = *(const short4_t*)&vrow[c * 16];
                o[0][nh] = __builtin_amdgcn_mfma_f32_16x16x16bf16_1k(pa[0][c], bv, o[0][nh], 0, 0, 0);
                o[1][nh] = __builtin_amdgcn_mfma_f32_16x16x16bf16_1k(pa[1][c], bv, o[1][nh], 0, 0, 0);
            }
        }
#else
        // fallback: LDS C->A transform (R8 path); note S^T means psw holds P^T,
        // so write transposed: row index = s-local, col = q-local.
        short* psw = ps + w * 16 * 72;
        short8 ap[2][2];
        for (int mt = 0; mt < 2; mt++) {
            int q_idx = trow0 + mt * 16 + l16;
            for (int nt = 0; nt < 4; nt++)
                for (int r = 0; r < 4; r++) {
                    float pv = exp2f(fmaf(sacc[mt][nt][r], C1, -C2));
                    int s_idx = s0 + nt * 16 + quad * 4 + r;
                    if (diag && (s_idx > q_idx)) pv = 0.0f;
                    lp[mt] += pv;
                    psw[l16 * 72 + nt * 16 + quad * 4 + r] = f2bf(pv);
                }
            ap[mt][0] = *(const short8*)&psw[l16 * 72 + quad * 8];
            ap[mt][1] = *(const short8*)&psw[l16 * 72 + 32 + quad * 8];
        }
        for (int nh = 0; nh < 4; nh++) {
            short8 bv0 = *(const short8*)&vsp[(nh * 16 + l16) * 72 + quad * 8];
            short8 bv1 = *(const short8*)&vsp[(nh * 16 + l16) * 72 + 32 + quad * 8];
            o[0][nh] = __builtin_amdgcn_mfma_f32_16x16x32_bf16(ap[0][0], bv0, o[0][nh], 0, 0, 0);
            o[0][nh] = __builtin_amdgcn_mfma_f32_16x16x32_bf16(ap[0][1], bv1, o[0][nh], 0, 0, 0);
            o[1][nh] = __builtin_amdgcn_mfma_f32_16x16x32_bf16(ap[1][0], bv0, o[1][nh], 0, 0, 0);
            o[1][nh] = __builtin_amdgcn_mfma_f32_16x16x32_bf16(ap[1][1], bv1, o[1][nh], 0, 0, 0);
        }
#endif

        if (more) {
            short* kd = ks + (1 - p) * KVSZ;
            short* vd = vs + (1 - p) * KVSZ;
            *(short8*)&kd[srow * 72 + soff] = pk0;
            *(short8*)&kd[(srow + 32) * 72 + soff] = pk1;
            *(short8*)&vd[srow * 72 + soff] = pv0;
            *(short8*)&vd[(srow + 32) * 72 + soff] = pv1;
            __syncthreads();
            p ^= 1;
        }
    }

    // l lives at lane l16 = q, partial over quads: reduce across quads.
    for (int mt = 0; mt < 2; mt++) {
        lp[mt] += __shfl_xor(lp[mt], 16);
        lp[mt] += __shfl_xor(lp[mt], 32);
    }

    char* slotb = (char*)slots + ((size_t)b * nslot + fid) * SLOT_BYTES;
    short* slotO = (short*)slotb;
    float* slotL = (float*)(slotb + 16384);

    // O C-layout: col(l16) = h-within-16, row(quad*4+r) = q-within-16.
    for (int mt = 0; mt < 2; mt++)
        for (int nh = 0; nh < 4; nh++)
            for (int r = 0; r < 4; r++)
                slotO[(w * 32 + mt * 16 + quad * 4 + r) * 64 + nh * 16 + l16] = f2bf(o[mt][nh][r]);
    if (quad == 0)
        for (int mt = 0; mt < 2; mt++)
            slotL[w * 32 + mt * 16 + l16] = lp[mt];
}

// ---------------------------------------------------------------------------
// Kernel 2b: combine. Block = (tt, b), 128 rows; bf16 slot O, fp32 l.
// ---------------------------------------------------------------------------
__global__ __launch_bounds__(256) void combine_kernel(
        const float* __restrict__ slots, int nslot, float* __restrict__ out) {
    int b = blockIdx.y, tt = blockIdx.x;
    int nseg = (2 * tt + 5) >> 2;
    int cum = 0;
    for (int i = 0; i < tt; i++) cum += (2 * i + 5) >> 2;
    const char* base = (const char*)slots + ((size_t)b * nslot + cum) * SLOT_BYTES;

    int tid = threadIdx.x;
    int row = tid >> 1, half = tid & 1;
    float acc[32];
    for (int i = 0; i < 32; i++) acc[i] = 0.f;
    float lsum = 0.f;
    for (int s = 0; s < nseg; s++) {
        const short* O = (const short*)(base + (size_t)s * SLOT_BYTES);
        const float* L = (const float*)(base + (size_t)s * SLOT_BYTES + 16384);
        for (int i = 0; i < 4; i++) {
            short8 v = *(const short8*)&O[row * 64 + half * 32 + i * 8];
            for (int j = 0; j < 8; j++) acc[i * 8 + j] += bf2f(v[j]);
        }
        lsum += L[row];
    }
    float inv = 1.0f / lsum;
    float* op = out + (size_t)(b * T_ + tt * 128 + row) * H_ + half * 32;
    for (int i = 0; i < 8; i++) {
        float4 v;
        v.x = acc[i * 4 + 0] * inv; v.y = acc[i * 4 + 1] * inv;
        v.z = acc[i * 4 + 2] * inv; v.w = acc[i * 4 + 3] * inv;
        *(float4*)&op[i * 4] = v;
    }
}

// ---------------------------------------------------------------------------
// Fallback direct attention (used only if ws too small) — unchanged R8 path.
// ---------------------------------------------------------------------------
template<bool DIAG>
static __device__ __forceinline__ void attn_step(
        int s0, int t0w, int quad, int l16,
        const short* __restrict__ kbase, const short* __restrict__ vtb,
        short8 aq0, short8 aq1, short* __restrict__ psw,
        floatx4 (&o)[4], float (&lpart)[4]) {
    floatx4 sacc[4];
    for (int nt = 0; nt < 4; nt++) sacc[nt] = (floatx4)0.0f;
    for (int nt = 0; nt < 4; nt++) {
        short8 bk0 = *(const short8*)&kbase[(nt * 16 + l16) * H_ + quad * 8];
        short8 bk1 = *(const short8*)&kbase[(nt * 16 + l16) * H_ + 32 + quad * 8];
        sacc[nt] = __builtin_amdgcn_mfma_f32_16x16x32_bf16(aq0, bk0, sacc[nt], 0, 0, 0);
        sacc[nt] = __builtin_amdgcn_mfma_f32_16x16x32_bf16(aq1, bk1, sacc[nt], 0, 0, 0);
    }
    const float C1 = 0.125f * 1.44269504f;
    const float C2 = 12.0f * 1.44269504f;
    for (int nt = 0; nt < 4; nt++) {
        int s_idx = s0 + nt * 16 + l16;
        for (int r = 0; r < 4; r++) {
            float p = exp2f(fmaf(sacc[nt][r], C1, -C2));
            if (DIAG && (s_idx > t0w + quad * 4 + r)) p = 0.0f;
            lpart[r] += p;
            psw[(quad * 4 + r) * 72 + nt * 16 + l16] = f2bf(p);
        }
    }
    short8 ap0 = *(const short8*)&psw[l16 * 72 + quad * 8];
    short8 ap1 = *(const short8*)&psw[l16 * 72 + 32 + quad * 8];
    for (int nh = 0; nh < 4; nh++) {
        short8 bv0 = *(const short8*)&vtb[(size_t)(nh * 16 + l16) * T_ + s0 + quad * 8];
        short8 bv1 = *(const short8*)&vtb[(size_t)(nh * 16 + l16) * T_ + s0 + 32 + quad * 8];
        o[nh] = __builtin_amdgcn_mfma_f32_16x16x32_bf16(ap0, bv0, o[nh], 0, 0, 0);
        o[nh] = __builtin_amdgcn_mfma_f32_16x16x32_bf16(ap1, bv1, o[nh], 0, 0, 0);
    }
}

__global__ __launch_bounds__(256) void attn_kernel(
        const short* __restrict__ q, const short* __restrict__ k,
        const short* __restrict__ vt, float* __restrict__ out) {
    __shared__ short ps[4 * 16 * 72];

    int b = blockIdx.y;
    int g = ((int)blockIdx.x + 4 * (b & 7)) & 31;
    int tt = (b < 8) ? g : 31 - g;
    int t0 = tt * 64;
    int tid = threadIdx.x, w = tid >> 6, lane = tid & 63, quad = lane >> 4, l16 = lane & 15;
    int t0w = t0 + w * 16;

    const short* qrow = q + (size_t)(b * T_ + t0w + l16) * H_;
    short8 aq0 = *(const short8*)&qrow[quad * 8];
    short8 aq1 = *(const short8*)&qrow[32 + quad * 8];

    floatx4 o[4];
    for (int nh = 0; nh < 4; nh++) o[nh] = (floatx4)0.0f;
    float lpart[4] = {0.f, 0.f, 0.f, 0.f};

    const short* kb0 = k + (size_t)b * T_ * H_;
    const short* vtb = vt + (size_t)b * H_ * T_;
    short* psw = ps + w * 16 * 72;

    for (int st = 0; st < tt; st++)
        attn_step<false>(st * 64, t0w, quad, l16, kb0 + (size_t)st * 64 * H_,
                         vtb, aq0, aq1, psw, o, lpart);
    attn_step<true>(tt * 64, t0w, quad, l16, kb0 + (size_t)tt * 64 * H_,
                    vtb, aq0, aq1, psw, o, lpart);

    for (int d = 1; d < 16; d <<= 1)
        for (int r = 0; r < 4; r++)
            lpart[r] += __shfl_xor(lpart[r], d, 16);

    for (int nh = 0; nh < 4; nh++)
        for (int r = 0; r < 4; r++) {
            int t = t0w + quad * 4 + r;
            out[(size_t)(b * T_ + t) * H_ + nh * 16 + l16] = o[nh][r] / lpart[r];
        }
}

// ---------------------------------------------------------------------------
extern "C" void kernel_launch(void* const* d_in, const int* in_sizes, int n_in,
                              void* d_out, int out_size, void* d_ws, size_t ws_size,
                              hipStream_t stream) {
    const float* x  = (const float*)d_in[0];
    const float* Wq = (const float*)d_in[1];
    const float* Wk = (const float*)d_in[2];
    const float* Wv = (const float*)d_in[3];

    char* ws = (char*)d_ws;
    short* qb  = (short*)(ws);                                  // 4 MB
    short* kb  = (short*)(ws + (size_t)4 * 1024 * 1024);        // 4 MB
    short* vtb = (short*)(ws + (size_t)8 * 1024 * 1024);        // 4 MB, [B][H][T]
    short* wtb = (short*)(ws + (size_t)12 * 1024 * 1024);       // 144 KB (frag order)
    float* slots = (float*)(ws + (size_t)12 * 1024 * 1024 + 256 * 1024);
    size_t base_need = (size_t)12 * 1024 * 1024 + 256 * 1024;

    wt_kernel<<<dim3(288), dim3(256), 0, stream>>>(Wq, Wk, Wv, wtb);
    qkv_kernel<<<dim3(T_ / 32, B_), dim3(256), 0, stream>>>(x, wtb, qb, kb, vtb);

    float* out = (float*)d_out;
    const int NSLOT = 72;   // sum_{tt=0}^{15} ceil((2tt+2)/4)
    if (ws_size >= base_need + (size_t)B_ * NSLOT * (size_t)SLOT_BYTES) {
        attn_seg_kernel<<<dim3(NSLOT, B_), dim3(256), 0, stream>>>(qb, kb, vtb, slots);
        combine_kernel<<<dim3(T_ / 128, B_), dim3(256), 0, stream>>>(slots, NSLOT, out);
    } else {
        attn_kernel<<<dim3(T_ / 64, B_), dim3(256), 0, stream>>>(qb, kb, vtb, out);
    }
}